// Round 1
// baseline (440.661 us; speedup 1.0000x reference)
//
#include <hip/hip_runtime.h>
#include <hip/hip_bf16.h>

typedef unsigned short u16;
using bf16x8 = __bf16 __attribute__((ext_vector_type(8)));
using f32x4  = float  __attribute__((ext_vector_type(4)));

#define BB 4
#define TT 4096
#define DD 1024
#define MROWS (BB*TT)   /* 16384 */
#define CT 64           /* scan chunk length */
#define NC (TT/CT)      /* 64 chunks */

__device__ __forceinline__ float sigm(float x) { return 1.0f / (1.0f + __expf(-x)); }
__device__ __forceinline__ u16 f2bf(float f) {
    __hip_bfloat16 h = __float2bfloat16(f);
    return *reinterpret_cast<u16*>(&h);
}
__device__ __forceinline__ float bf2f(u16 u) { return __uint_as_float(((unsigned)u) << 16); }

// ---------------------------------------------------------------- converts
__global__ __launch_bounds__(256) void conv_x_kernel(const float* __restrict__ s,
                                                     u16* __restrict__ d) {
    size_t i = (size_t)blockIdx.x * 256 + threadIdx.x;   // one float4 per thread
    float4 v = *(const float4*)(s + i * 4);
    ushort4 u;
    u.x = f2bf(v.x); u.y = f2bf(v.y); u.z = f2bf(v.z); u.w = f2bf(v.w);
    *(ushort4*)(d + i * 4) = u;
}

__global__ __launch_bounds__(256) void conv_w4_kernel(const float* __restrict__ w0,
                                                      const float* __restrict__ w1,
                                                      const float* __restrict__ w2,
                                                      const float* __restrict__ w3,
                                                      u16* __restrict__ dst) {
    int i = blockIdx.x * 256 + threadIdx.x;  // 0 .. 4*2^18-1 float4s
    int sel = i >> 18;                       // 2^18 float4 per 1024x1024 weight
    int off = i & 262143;
    const float* s = (sel == 0) ? w0 : (sel == 1) ? w1 : (sel == 2) ? w2 : w3;
    float4 v = *(const float4*)(s + (size_t)off * 4);
    ushort4 u;
    u.x = f2bf(v.x); u.y = f2bf(v.y); u.z = f2bf(v.z); u.w = f2bf(v.w);
    *(ushort4*)(dst + ((size_t)sel << 20) + (size_t)off * 4) = u;
}

// ---------------------------------------------------------------- GEMM
// C[m][n] = sum_k A[m][k] * W[n][k], A:[M,K] bf16 row-major, W:[N,K] bf16 row-major.
// 128x128 tile, BK=64, 4 waves (2x2), each wave 64x64 via 4x4 mfma_f32_16x16x32_bf16.
// LDS XOR-swizzle: row m, 16B-granule g stored at physical granule (g ^ (m&7)).
// Output planes are 1024-wide fp32; plane index = global_n / 1024.
#define BM 128
#define BN 128
#define BK 64

__global__ __launch_bounds__(256, 2)
void gemm_bf16_bt(const u16* __restrict__ Ag, const u16* __restrict__ Bg, int K,
                  float* __restrict__ P0, float* __restrict__ P1, float* __restrict__ P2) {
    __shared__ u16 As[BM * BK];
    __shared__ u16 Bs[BN * BK];

    const int tid  = threadIdx.x;
    const int lane = tid & 63;
    const int wid  = tid >> 6;
    const int wm   = wid >> 1;      // wave row 0..1
    const int wn   = wid & 1;       // wave col 0..1
    const int lr   = lane & 15;
    const int lq   = lane >> 4;

    const long bM  = (long)blockIdx.y * BM;
    const long bN0 = (long)blockIdx.x * BN;

    const f32x4 zero = {0.f, 0.f, 0.f, 0.f};
    f32x4 acc[4][4];
#pragma unroll
    for (int i = 0; i < 4; i++)
#pragma unroll
        for (int j = 0; j < 4; j++) acc[i][j] = zero;

    for (int kt = 0; kt < K; kt += BK) {
        __syncthreads();
#pragma unroll
        for (int j = 0; j < 4; j++) {
            const int G  = j * 256 + tid;     // granule id 0..1023
            const int m  = G >> 3;            // row 0..127
            const int p  = G & 7;             // physical granule
            const int gk = p ^ (m & 7);       // logical k-granule (swizzle)
            *(int4*)(&As[G * 8]) = *(const int4*)(Ag + (bM + m) * K + kt + gk * 8);
            *(int4*)(&Bs[G * 8]) = *(const int4*)(Bg + (bN0 + m) * K + kt + gk * 8);
        }
        __syncthreads();
#pragma unroll
        for (int kk = 0; kk < BK / 32; kk++) {
            bf16x8 av[4], bv[4];
#pragma unroll
            for (int f = 0; f < 4; f++) {
                const int am = wm * 64 + f * 16 + lr;
                const int ag = (kk * 4 + lq) ^ (am & 7);
                av[f] = *(const bf16x8*)(&As[am * 64 + ag * 8]);
                const int bn = wn * 64 + f * 16 + lr;
                const int bg = (kk * 4 + lq) ^ (bn & 7);
                bv[f] = *(const bf16x8*)(&Bs[bn * 64 + bg * 8]);
            }
#pragma unroll
            for (int i = 0; i < 4; i++)
#pragma unroll
                for (int j = 0; j < 4; j++)
                    acc[i][j] = __builtin_amdgcn_mfma_f32_16x16x32_bf16(av[i], bv[j],
                                                                        acc[i][j], 0, 0, 0);
        }
    }

    const int pl = (int)(bN0 >> 10);   // BN=128 divides 1024 -> whole block in one plane
    float* P = (pl == 0) ? P0 : ((pl == 1) ? P1 : P2);
    const int cn = (int)(bN0 & 1023);
#pragma unroll
    for (int i = 0; i < 4; i++) {
        const long m0 = bM + wm * 64 + i * 16 + lq * 4;
#pragma unroll
        for (int j = 0; j < 4; j++) {
            const int n = cn + wn * 64 + j * 16 + lr;
#pragma unroll
            for (int r = 0; r < 4; r++)
                P[(m0 + r) * 1024 + n] = acc[i][j][r];
        }
    }
}

// ---------------------------------------------------------------- chunked scan
// h_t = f_t * h_{t-1} + silu(i_t)*(1-f_t),  f = sigmoid(f_pre)
__global__ __launch_bounds__(256) void scan_pass1(const float* __restrict__ ip,
                                                  const float* __restrict__ fp,
                                                  float* __restrict__ Fc,
                                                  float* __restrict__ Ic) {
    const int tid = blockIdx.x * 256 + threadIdx.x;  // B*NC*D threads
    const int d = tid & 1023;
    const int c = (tid >> 10) & (NC - 1);
    const int b = tid >> 16;
    size_t base = ((size_t)(b * TT + c * CT) << 10) + d;
    float F = 1.f, I = 0.f;
#pragma unroll 8
    for (int t = 0; t < CT; t++) {
        float fv = fp[base];
        float iv = ip[base];
        base += DD;
        float f = sigm(fv);
        float v = iv * sigm(iv) * (1.f - f);
        I = fmaf(f, I, v);
        F *= f;
    }
    Fc[tid] = F;
    Ic[tid] = I;
}

__global__ __launch_bounds__(256) void scan_pass2(const float* __restrict__ Fc,
                                                  const float* __restrict__ Ic,
                                                  float* __restrict__ Hin) {
    const int tid = blockIdx.x * 256 + threadIdx.x;  // B*D threads
    const int d = tid & 1023;
    const int b = tid >> 10;
    float H = 0.f;
    for (int c = 0; c < NC; c++) {
        const int idx = ((b * NC + c) << 10) + d;
        Hin[idx] = H;
        H = fmaf(Fc[idx], H, Ic[idx]);
    }
}

__global__ __launch_bounds__(256) void scan_pass3(const float* __restrict__ ip,
                                                  const float* __restrict__ fp,
                                                  const float* __restrict__ Hin,
                                                  u16* __restrict__ hout) {
    const int tid = blockIdx.x * 256 + threadIdx.x;
    const int d = tid & 1023;
    const int c = (tid >> 10) & (NC - 1);
    const int b = tid >> 16;
    size_t base = ((size_t)(b * TT + c * CT) << 10) + d;
    float h = Hin[tid];
#pragma unroll 8
    for (int t = 0; t < CT; t++) {
        float fv = fp[base];
        float iv = ip[base];
        float f = sigm(fv);
        float v = iv * sigm(iv) * (1.f - f);
        h = fmaf(f, h, v);
        hout[base] = f2bf(h);
        base += DD;
    }
}

// ---------------------------------------------------------------- RMSNorm * swish(g)
// hin and oout alias (in-place): all h reads happen before the barrier, writes after.
__global__ __launch_bounds__(256) void rmsnorm_gate(const u16* hin,
                                                    const float* __restrict__ g,
                                                    const float* __restrict__ w,
                                                    u16* oout) {
    const int row = blockIdx.x;
    const int t = threadIdx.x;
    const size_t base = ((size_t)row << 10) + t * 4;
    ushort4 hu = *(const ushort4*)(hin + base);
    float h0 = bf2f(hu.x), h1 = bf2f(hu.y), h2 = bf2f(hu.z), h3 = bf2f(hu.w);
    float ss = h0 * h0 + h1 * h1 + h2 * h2 + h3 * h3;
#pragma unroll
    for (int o = 32; o > 0; o >>= 1) ss += __shfl_down(ss, o);
    __shared__ float red[4];
    if ((t & 63) == 0) red[t >> 6] = ss;
    __syncthreads();
    const float tot = red[0] + red[1] + red[2] + red[3];
    const float rms = rsqrtf(tot * (1.f / 1024.f) + 1e-5f);
    float4 gv = *(const float4*)(g + base);
    float4 wv = *(const float4*)(w + (size_t)t * 4);
    ushort4 ou;
    ou.x = f2bf(h0 * rms * wv.x * gv.x * sigm(gv.x));
    ou.y = f2bf(h1 * rms * wv.y * gv.y * sigm(gv.y));
    ou.z = f2bf(h2 * rms * wv.z * gv.z * sigm(gv.z));
    ou.w = f2bf(h3 * rms * wv.w * gv.w * sigm(gv.w));
    *(ushort4*)(oout + base) = ou;
}

// ---------------------------------------------------------------- launch
extern "C" void kernel_launch(void* const* d_in, const int* in_sizes, int n_in,
                              void* d_out, int out_size, void* d_ws, size_t ws_size,
                              hipStream_t stream) {
    const float* x  = (const float*)d_in[0];
    const float* Wi = (const float*)d_in[1];
    const float* Wf = (const float*)d_in[2];
    const float* Wg = (const float*)d_in[3];
    const float* Wo = (const float*)d_in[4];
    const float* nw = (const float*)d_in[5];
    float* out = (float*)d_out;

    const size_t MB = 1ull << 20;
    char* ws = (char*)d_ws;
    u16*   xo  = (u16*)(ws);              // 32MB: x_bf16, later h_bf16 then o_bf16
    u16*   Wb  = (u16*)(ws + 32 * MB);    // 8MB: [Wi;Wf;Wg;Wo] bf16, K-major rows
    float* Pi  = (float*)(ws + 40 * MB);  // 64MB: i_pre fp32
    float* Pf  = (float*)(ws + 104 * MB); // 64MB: f_pre fp32
    float* Fc  = (float*)(ws + 168 * MB); // 1MB
    float* Ic  = Fc + BB * NC * DD;       // 1MB
    float* Hin = Ic + BB * NC * DD;       // 1MB
    float* g   = (float*)d_out;           // g plane parked in d_out until final GEMM

    conv_x_kernel<<<16384, 256, 0, stream>>>(x, xo);
    conv_w4_kernel<<<4096, 256, 0, stream>>>(Wi, Wf, Wg, Wo, Wb);
    // i_pre / f_pre / g in one GEMM: N=3072
    gemm_bf16_bt<<<dim3(24, 128), 256, 0, stream>>>(xo, Wb, 1024, Pi, Pf, g);
    scan_pass1<<<1024, 256, 0, stream>>>(Pi, Pf, Fc, Ic);
    scan_pass2<<<16, 256, 0, stream>>>(Fc, Ic, Hin);
    scan_pass3<<<1024, 256, 0, stream>>>(Pi, Pf, Hin, xo);
    rmsnorm_gate<<<16384, 256, 0, stream>>>(xo, g, nw, xo);
    // out = o @ Wo^T
    gemm_bf16_bt<<<dim3(8, 128), 256, 0, stream>>>(xo, Wb + 3ull * 1024 * 1024, 1024,
                                                   out, out, out);
}

// Round 2
// 364.668 us; speedup vs baseline: 1.2084x; 1.2084x over previous
//
#include <hip/hip_runtime.h>
#include <hip/hip_bf16.h>

typedef unsigned short u16;
using bf16x8 = __bf16 __attribute__((ext_vector_type(8)));
using f32x4  = float  __attribute__((ext_vector_type(4)));

#define BB 4
#define TT 4096
#define DD 1024
#define MROWS (BB*TT)   /* 16384 */
#define CT 64           /* scan chunk length */
#define NC (TT/CT)      /* 64 chunks */

__device__ __forceinline__ float sigm(float x) { return 1.0f / (1.0f + __expf(-x)); }
__device__ __forceinline__ u16 f2bf(float f) {
    __hip_bfloat16 h = __float2bfloat16(f);
    return *reinterpret_cast<u16*>(&h);
}
__device__ __forceinline__ float bf2f(u16 u) { return __uint_as_float(((unsigned)u) << 16); }

// async 16B global->LDS (direct-to-shared DMA; LDS dest must be wave-uniform base + lane*16)
__device__ __forceinline__ void async_cp16(const u16* g, u16* l) {
    __builtin_amdgcn_global_load_lds(
        (const __attribute__((address_space(1))) unsigned int*)g,
        (__attribute__((address_space(3))) unsigned int*)l, 16, 0, 0);
}

// ---------------------------------------------------------------- converts
__global__ __launch_bounds__(256) void conv_x_kernel(const float* __restrict__ s,
                                                     u16* __restrict__ d) {
    size_t i = (size_t)blockIdx.x * 256 + threadIdx.x;   // one float4 per thread
    float4 v = *(const float4*)(s + i * 4);
    ushort4 u;
    u.x = f2bf(v.x); u.y = f2bf(v.y); u.z = f2bf(v.z); u.w = f2bf(v.w);
    *(ushort4*)(d + i * 4) = u;
}

__global__ __launch_bounds__(256) void conv_w4_kernel(const float* __restrict__ w0,
                                                      const float* __restrict__ w1,
                                                      const float* __restrict__ w2,
                                                      const float* __restrict__ w3,
                                                      u16* __restrict__ dst) {
    int i = blockIdx.x * 256 + threadIdx.x;  // 0 .. 4*2^18-1 float4s
    int sel = i >> 18;                       // 2^18 float4 per 1024x1024 weight
    int off = i & 262143;
    const float* s = (sel == 0) ? w0 : (sel == 1) ? w1 : (sel == 2) ? w2 : w3;
    float4 v = *(const float4*)(s + (size_t)off * 4);
    ushort4 u;
    u.x = f2bf(v.x); u.y = f2bf(v.y); u.z = f2bf(v.z); u.w = f2bf(v.w);
    *(ushort4*)(dst + ((size_t)sel << 20) + (size_t)off * 4) = u;
}

// ---------------------------------------------------------------- GEMM
// C[m][n] = sum_k A[m][k] * W[n][k], A:[M,K] bf16 row-major, W:[N,K] bf16 row-major.
// 128x128 tile, BK=64, 4 waves (2x2), each wave 64x64 via 4x4 mfma_f32_16x16x32_bf16.
// LDS XOR-swizzle: physical granule p of row m holds logical k-granule p^(m&7)
// (swizzle applied on the GLOBAL address side so global_load_lds's
//  wave-uniform-base+lane*16 LDS pattern is contiguous). R0: 0 bank conflicts.
#define BM 128
#define BN 128
#define BK 64

template <typename OutT>
__global__ __launch_bounds__(256, 2)
void gemm_bf16_bt(const u16* __restrict__ Ag, const u16* __restrict__ Bg, int K,
                  OutT* __restrict__ P0, OutT* __restrict__ P1, OutT* __restrict__ P2) {
    __shared__ u16 As[BM * BK];
    __shared__ u16 Bs[BN * BK];

    const int tid  = threadIdx.x;
    const int lane = tid & 63;
    const int wid  = tid >> 6;
    const int wm   = wid >> 1;      // wave row 0..1
    const int wn   = wid & 1;       // wave col 0..1
    const int lr   = lane & 15;
    const int lq   = lane >> 4;

    const long bM  = (long)blockIdx.y * BM;
    const long bN0 = (long)blockIdx.x * BN;

    const f32x4 zero = {0.f, 0.f, 0.f, 0.f};
    f32x4 acc[4][4];
#pragma unroll
    for (int i = 0; i < 4; i++)
#pragma unroll
        for (int j = 0; j < 4; j++) acc[i][j] = zero;

    for (int kt = 0; kt < K; kt += BK) {
        __syncthreads();
#pragma unroll
        for (int j = 0; j < 4; j++) {
            const int G  = j * 256 + tid;     // LDS granule = wave_base + lane (contiguous)
            const int m  = G >> 3;            // row 0..127
            const int p  = G & 7;             // physical granule
            const int gk = p ^ (m & 7);       // logical k-granule (swizzle on global side)
            async_cp16(Ag + (bM + m) * K + kt + gk * 8, &As[G * 8]);
            async_cp16(Bg + (bN0 + m) * K + kt + gk * 8, &Bs[G * 8]);
        }
        __syncthreads();   // compiler emits s_waitcnt vmcnt(0) before s_barrier
#pragma unroll
        for (int kk = 0; kk < BK / 32; kk++) {
            bf16x8 av[4], bv[4];
#pragma unroll
            for (int f = 0; f < 4; f++) {
                const int am = wm * 64 + f * 16 + lr;
                const int ag = (kk * 4 + lq) ^ (am & 7);
                av[f] = *(const bf16x8*)(&As[am * 64 + ag * 8]);
                const int bn = wn * 64 + f * 16 + lr;
                const int bg = (kk * 4 + lq) ^ (bn & 7);
                bv[f] = *(const bf16x8*)(&Bs[bn * 64 + bg * 8]);
            }
#pragma unroll
            for (int i = 0; i < 4; i++)
#pragma unroll
                for (int j = 0; j < 4; j++)
                    acc[i][j] = __builtin_amdgcn_mfma_f32_16x16x32_bf16(av[i], bv[j],
                                                                        acc[i][j], 0, 0, 0);
        }
    }

    const int pl = (int)(bN0 >> 10);   // BN=128 divides 1024 -> whole block in one plane
    OutT* P = (pl == 0) ? P0 : ((pl == 1) ? P1 : P2);
    const int cn = (int)(bN0 & 1023);
#pragma unroll
    for (int i = 0; i < 4; i++) {
        const long m0 = bM + wm * 64 + i * 16 + lq * 4;
#pragma unroll
        for (int j = 0; j < 4; j++) {
            const int n = cn + wn * 64 + j * 16 + lr;
#pragma unroll
            for (int r = 0; r < 4; r++) {
                if constexpr (sizeof(OutT) == 2)
                    P[(m0 + r) * 1024 + n] = f2bf(acc[i][j][r]);
                else
                    P[(m0 + r) * 1024 + n] = acc[i][j][r];
            }
        }
    }
}

// ---------------------------------------------------------------- chunked scan
// h_t = f_t * h_{t-1} + silu(i_t)*(1-f_t),  f = sigmoid(f_pre); planes are bf16
__global__ __launch_bounds__(256) void scan_pass1(const u16* __restrict__ ip,
                                                  const u16* __restrict__ fp,
                                                  float* __restrict__ Fc,
                                                  float* __restrict__ Ic) {
    const int tid = blockIdx.x * 256 + threadIdx.x;  // B*NC*D threads
    const int d = tid & 1023;
    const int c = (tid >> 10) & (NC - 1);
    const int b = tid >> 16;
    size_t base = ((size_t)(b * TT + c * CT) << 10) + d;
    float F = 1.f, I = 0.f;
#pragma unroll 8
    for (int t = 0; t < CT; t++) {
        float fv = bf2f(fp[base]);
        float iv = bf2f(ip[base]);
        base += DD;
        float f = sigm(fv);
        float v = iv * sigm(iv) * (1.f - f);
        I = fmaf(f, I, v);
        F *= f;
    }
    Fc[tid] = F;
    Ic[tid] = I;
}

__global__ __launch_bounds__(256) void scan_pass2(const float* __restrict__ Fc,
                                                  const float* __restrict__ Ic,
                                                  float* __restrict__ Hin) {
    const int tid = blockIdx.x * 256 + threadIdx.x;  // B*D threads
    const int d = tid & 1023;
    const int b = tid >> 10;
    float H = 0.f;
    for (int c = 0; c < NC; c++) {
        const int idx = ((b * NC + c) << 10) + d;
        Hin[idx] = H;
        H = fmaf(Fc[idx], H, Ic[idx]);
    }
}

__global__ __launch_bounds__(256) void scan_pass3(const u16* __restrict__ ip,
                                                  const u16* __restrict__ fp,
                                                  const float* __restrict__ Hin,
                                                  u16* __restrict__ hout) {
    const int tid = blockIdx.x * 256 + threadIdx.x;
    const int d = tid & 1023;
    const int c = (tid >> 10) & (NC - 1);
    const int b = tid >> 16;
    size_t base = ((size_t)(b * TT + c * CT) << 10) + d;
    float h = Hin[tid];
#pragma unroll 8
    for (int t = 0; t < CT; t++) {
        float fv = bf2f(fp[base]);
        float iv = bf2f(ip[base]);
        float f = sigm(fv);
        float v = iv * sigm(iv) * (1.f - f);
        h = fmaf(f, h, v);
        hout[base] = f2bf(h);
        base += DD;
    }
}

// ---------------------------------------------------------------- RMSNorm * swish(g)
// hin and oout alias (in-place): all h reads happen before the barrier, writes after.
__global__ __launch_bounds__(256) void rmsnorm_gate(const u16* hin,
                                                    const u16* __restrict__ g,
                                                    const float* __restrict__ w,
                                                    u16* oout) {
    const int row = blockIdx.x;
    const int t = threadIdx.x;
    const size_t base = ((size_t)row << 10) + t * 4;
    ushort4 hu = *(const ushort4*)(hin + base);
    float h0 = bf2f(hu.x), h1 = bf2f(hu.y), h2 = bf2f(hu.z), h3 = bf2f(hu.w);
    float ss = h0 * h0 + h1 * h1 + h2 * h2 + h3 * h3;
#pragma unroll
    for (int o = 32; o > 0; o >>= 1) ss += __shfl_down(ss, o);
    __shared__ float red[4];
    if ((t & 63) == 0) red[t >> 6] = ss;
    __syncthreads();
    const float tot = red[0] + red[1] + red[2] + red[3];
    const float rms = rsqrtf(tot * (1.f / 1024.f) + 1e-5f);
    ushort4 gu = *(const ushort4*)(g + base);
    float g0 = bf2f(gu.x), g1 = bf2f(gu.y), g2 = bf2f(gu.z), g3 = bf2f(gu.w);
    float4 wv = *(const float4*)(w + (size_t)t * 4);
    ushort4 ou;
    ou.x = f2bf(h0 * rms * wv.x * g0 * sigm(g0));
    ou.y = f2bf(h1 * rms * wv.y * g1 * sigm(g1));
    ou.z = f2bf(h2 * rms * wv.z * g2 * sigm(g2));
    ou.w = f2bf(h3 * rms * wv.w * g3 * sigm(g3));
    *(ushort4*)(oout + base) = ou;
}

// ---------------------------------------------------------------- launch
extern "C" void kernel_launch(void* const* d_in, const int* in_sizes, int n_in,
                              void* d_out, int out_size, void* d_ws, size_t ws_size,
                              hipStream_t stream) {
    const float* x  = (const float*)d_in[0];
    const float* Wi = (const float*)d_in[1];
    const float* Wf = (const float*)d_in[2];
    const float* Wg = (const float*)d_in[3];
    const float* Wo = (const float*)d_in[4];
    const float* nw = (const float*)d_in[5];
    float* out = (float*)d_out;

    const size_t MB = 1ull << 20;
    char* ws = (char*)d_ws;
    u16*   xo  = (u16*)(ws);              // 32MB: x_bf16, later h_bf16 then o_bf16
    u16*   Wb  = (u16*)(ws + 32 * MB);    // 8MB: [Wi;Wf;Wg;Wo] bf16, K-major rows
    u16*   Pi  = (u16*)(ws + 40 * MB);    // 32MB: i_pre bf16
    u16*   Pf  = (u16*)(ws + 72 * MB);    // 32MB: f_pre bf16
    float* Fc  = (float*)(ws + 104 * MB); // 1MB
    float* Ic  = Fc + BB * NC * DD;       // 1MB
    float* Hin = Ic + BB * NC * DD;       // 1MB
    u16*   g   = (u16*)d_out;             // g plane (bf16) parked in d_out until final GEMM

    conv_x_kernel<<<16384, 256, 0, stream>>>(x, xo);
    conv_w4_kernel<<<4096, 256, 0, stream>>>(Wi, Wf, Wg, Wo, Wb);
    // i_pre / f_pre / g in one GEMM: N=3072
    gemm_bf16_bt<u16><<<dim3(24, 128), 256, 0, stream>>>(xo, Wb, 1024, Pi, Pf, g);
    scan_pass1<<<1024, 256, 0, stream>>>(Pi, Pf, Fc, Ic);
    scan_pass2<<<16, 256, 0, stream>>>(Fc, Ic, Hin);
    scan_pass3<<<1024, 256, 0, stream>>>(Pi, Pf, Hin, xo);
    rmsnorm_gate<<<16384, 256, 0, stream>>>(xo, g, nw, xo);
    // out = o @ Wo^T
    gemm_bf16_bt<float><<<dim3(8, 128), 256, 0, stream>>>(xo, Wb + 3ull * 1024 * 1024, 1024,
                                                          out, out, out);
}